// Round 1
// 687.902 us; speedup vs baseline: 1.1549x; 1.1549x over previous
//
#include <hip/hip_runtime.h>
#include <cstdint>
#include <cstddef>

#define B_   2
#define S_   2048
#define D_   1024
#define HQ_  16
#define HKV_ 4
#define HD_  64
#define P_   4096

using frag8 = __attribute__((ext_vector_type(8))) short;   // 8 bf16 (4 VGPRs)
using f32x4 = __attribute__((ext_vector_type(4))) float;   // 4 fp32 acc

__device__ __forceinline__ uint16_t f2b(float f) {
  uint32_t u = __builtin_bit_cast(uint32_t, f);
  u += 0x7fffu + ((u >> 16) & 1u);          // RNE
  return (uint16_t)(u >> 16);
}
__device__ __forceinline__ float b2f(uint16_t h) {
  return __builtin_bit_cast(float, (uint32_t)h << 16);
}

// dtype-dispatched scalar load/store (F32: buffers are float; else bf16)
template <bool F32>
__device__ __forceinline__ float ldv(const void* p, size_t i) {
  if constexpr (F32) return ((const float*)p)[i];
  else return b2f(((const uint16_t*)p)[i]);
}
template <bool F32>
__device__ __forceinline__ void stv(void* p, size_t i, float v) {
  if constexpr (F32) ((float*)p)[i] = v;
  else ((uint16_t*)p)[i] = f2b(v);
}

// ---------------- DPP 16-lane (row) reductions: VALU-speed, no LDS pipe ----------------
// quad_perm xor1 = [1,0,3,2] = 0xB1 ; quad_perm xor2 = [2,3,0,1] = 0x4E
// row_ror:4 = 0x124 ; row_ror:8 = 0x128  (rotation within a 16-lane DPP row)
template <int CTRL>
__device__ __forceinline__ float fdpp(float x) {
  int v = __builtin_amdgcn_mov_dpp(__builtin_bit_cast(int, x), CTRL, 0xf, 0xf, true);
  return __builtin_bit_cast(float, v);
}
__device__ __forceinline__ float row16_max(float x) {
  x = fmaxf(x, fdpp<0xB1>(x));    // xor 1 (within quad)
  x = fmaxf(x, fdpp<0x4E>(x));    // xor 2 (within quad) -> quad max
  x = fmaxf(x, fdpp<0x124>(x));   // + quad j+1
  x = fmaxf(x, fdpp<0x128>(x));   // + quads j+2, j+3 -> full 16-lane max
  return x;
}
__device__ __forceinline__ float row16_sum(float x) {
  x += fdpp<0xB1>(x);
  x += fdpp<0x4E>(x);
  x += fdpp<0x124>(x);
  x += fdpp<0x128>(x);
  return x;
}

// XOR-swizzled byte offset into a 16x64 bf16 LDS tile (row stride 128 B).
// Flips bits 4..6 by row&7: spreads the 64-lane ds_read_b128 (all rows, same col
// range) across 8 bank-groups instead of 1, keeps 16 B alignment.
__device__ __forceinline__ int psw(int row, int col) {
  return (((row) << 7) + ((col) << 1)) ^ ((row & 7) << 4);
}

// ---------------- input dtype detector ----------------
__global__ void detect_kernel(const uint16_t* __restrict__ x, int* __restrict__ flag) {
  if (threadIdx.x == 0 && blockIdx.x == 0) {
    int sane = 0;
    for (int i = 0; i < 256; ++i) {
      uint16_t u = x[i];
      int e = (u >> 7) & 0xFF;
      if (u == 0 || (e >= 90 && e <= 141)) sane++;
    }
    *flag = (sane >= 240) ? 0 : 1;   // 0 = bf16, 1 = f32
  }
}

#define FLAG_CHECK() do { if (flag && *flag != (F32 ? 1 : 0)) return; } while (0)

// ---------------- RoPE cos/sin table: [S_][32] ----------------
__global__ __launch_bounds__(256) void rope_table_kernel(float* __restrict__ cosT,
                                                         float* __restrict__ sinT) {
  int i = blockIdx.x * 256 + threadIdx.x;       // 65536 entries
  int s = i >> 5, d = i & 31;
  float ang = (float)s * powf(10000.0f, -(float)d * (1.0f / 32.0f));
  cosT[i] = cosf(ang);
  sinT[i] = sinf(ang);
}

// ---------------- transpose: in (K x N, in-dtype) -> out (N x K, bf16) ----------------
template <bool F32>
__global__ __launch_bounds__(256) void transpose_k(const void* __restrict__ in,
                                                   uint16_t* __restrict__ out,
                                                   int K, int N, const int* __restrict__ flag) {
  FLAG_CHECK();
  __shared__ uint16_t tile[32][33];
  int n0 = blockIdx.x * 32, k0 = blockIdx.y * 32;
  int tx = threadIdx.x & 31, ty = threadIdx.x >> 5;   // ty 0..7
#pragma unroll
  for (int i = 0; i < 32; i += 8) {
    size_t idx = (size_t)(k0 + ty + i) * N + n0 + tx;
    tile[ty + i][tx] = F32 ? f2b(((const float*)in)[idx]) : ((const uint16_t*)in)[idx];
  }
  __syncthreads();
#pragma unroll
  for (int i = 0; i < 32; i += 8) out[(size_t)(n0 + ty + i) * K + k0 + tx] = tile[tx][ty + i];
}

// ---------------- LayerNorm (one block per row, D_=1024); output always bf16 ----------------
template <bool F32>
__global__ __launch_bounds__(256) void ln_kernel(const void* __restrict__ x,
                                                 const void* __restrict__ gamma,
                                                 const void* __restrict__ beta,
                                                 uint16_t* __restrict__ out,
                                                 const int* __restrict__ flag) {
  FLAG_CHECK();
  __shared__ float red[8];
  const int row = blockIdx.x;
  const int t = threadIdx.x;
  float f[4], s1 = 0.f, s2 = 0.f;
#pragma unroll
  for (int i = 0; i < 4; i++) {
    f[i] = ldv<F32>(x, (size_t)row * D_ + t * 4 + i);
    s1 += f[i]; s2 += f[i] * f[i];
  }
  for (int off = 1; off < 64; off <<= 1) { s1 += __shfl_xor(s1, off); s2 += __shfl_xor(s2, off); }
  int wave = t >> 6;
  if ((t & 63) == 0) { red[wave] = s1; red[4 + wave] = s2; }
  __syncthreads();
  s1 = red[0] + red[1] + red[2] + red[3];
  s2 = red[4] + red[5] + red[6] + red[7];
  float mean = s1 * (1.f / D_);
  float var = s2 * (1.f / D_) - mean * mean;
  float rstd = rsqrtf(var + 1e-5f);
  uint16_t ov[4];
#pragma unroll
  for (int i = 0; i < 4; i++) {
    float gv = ldv<F32>(gamma, t * 4 + i), bv = ldv<F32>(beta, t * 4 + i);
    ov[i] = f2b((f[i] - mean) * rstd * gv + bv);
  }
  *(uint64_t*)(out + (size_t)row * D_ + t * 4) = *(uint64_t*)ov;
}

// ---------------- GEMM: C(MxN) = A(MxK) @ Bt(NxK)^T, fused epilogues ----------------
enum { EPI_ROPE = 1, EPI_TRANSV = 2, EPI_GELU = 3, EPI_RES = 4, EPI_ACC = 5 };

template <int EPI, bool F32>
__global__ __launch_bounds__(256) void gemm_bt(const uint16_t* __restrict__ A, int lda,
                                               const uint16_t* __restrict__ Bt, int ldb,
                                               void* __restrict__ C, int ldc,
                                               int M, int N, int K,
                                               const float* __restrict__ cosT,
                                               const float* __restrict__ sinT,
                                               const void* __restrict__ bias, int bias_off,
                                               const void* __restrict__ res,
                                               const int* __restrict__ flag) {
  FLAG_CHECK();
  __shared__ __align__(16) uint16_t As[128 * 32];
  __shared__ __align__(16) uint16_t Bs[128 * 32];
  const int tid = threadIdx.x;
  const int wave = tid >> 6, lane = tid & 63;
  const int quad = lane >> 4, l15 = lane & 15;
  const int wm = wave >> 1, wn = wave & 1;
  const int bm = blockIdx.x * 128, bn = blockIdx.y * 128;

  const int ldr = tid >> 2;          // 0..63
  const int ldc8 = (tid & 3) * 8;    // 0,8,16,24
  const uint16_t* aptr = A + (size_t)(bm + ldr) * lda + ldc8;
  const uint16_t* bptr = Bt + (size_t)(bn + ldr) * ldb + ldc8;

  f32x4 acc[4][4];
  f32x4 zero = {0.f, 0.f, 0.f, 0.f};
#pragma unroll
  for (int i = 0; i < 4; i++)
#pragma unroll
    for (int j = 0; j < 4; j++) acc[i][j] = zero;

  for (int k0 = 0; k0 < K; k0 += 32) {
    uint4 a0 = *(const uint4*)aptr;
    uint4 a1 = *(const uint4*)(aptr + (size_t)64 * lda);
    uint4 b0 = *(const uint4*)bptr;
    uint4 b1 = *(const uint4*)(bptr + (size_t)64 * ldb);
    aptr += 32; bptr += 32;
    __syncthreads();                     // previous-iter LDS reads done
    *(uint4*)&As[ldr * 32 + ldc8] = a0;
    *(uint4*)&As[(64 + ldr) * 32 + ldc8] = a1;
    *(uint4*)&Bs[ldr * 32 + ldc8] = b0;
    *(uint4*)&Bs[(64 + ldr) * 32 + ldc8] = b1;
    __syncthreads();
    frag8 af[4], bfr[4];
#pragma unroll
    for (int i = 0; i < 4; i++) {
      af[i]  = *(const frag8*)&As[(wm * 64 + i * 16 + l15) * 32 + quad * 8];
      bfr[i] = *(const frag8*)&Bs[(wn * 64 + i * 16 + l15) * 32 + quad * 8];
    }
#pragma unroll
    for (int mi = 0; mi < 4; mi++)
#pragma unroll
      for (int ni = 0; ni < 4; ni++)
        acc[mi][ni] = __builtin_amdgcn_mfma_f32_16x16x32_bf16(af[mi], bfr[ni], acc[mi][ni], 0, 0, 0);
  }

  const int row0 = bm + wm * 64 + quad * 4;
  const int col0 = bn + wn * 64 + l15;

  if constexpr (EPI == EPI_ROPE) {
#pragma unroll
    for (int mi = 0; mi < 4; ++mi)
#pragma unroll
      for (int r = 0; r < 4; ++r) {
        int row = row0 + mi * 16 + r;
        int s = row & (S_ - 1);
#pragma unroll
        for (int ni = 0; ni < 2; ++ni) {
          int d = ni * 16 + l15;
          float c = cosT[s * 32 + d], sn = sinT[s * 32 + d];
          float x1 = acc[mi][ni][r], x2 = acc[mi][ni + 2][r];
          size_t base = (size_t)row * ldc + col0 + ni * 16;
          ((uint16_t*)C)[base] = f2b(x1 * c - x2 * sn);
          ((uint16_t*)C)[base + 32] = f2b(x1 * sn + x2 * c);
        }
      }
  } else if constexpr (EPI == EPI_TRANSV) {
#pragma unroll
    for (int mi = 0; mi < 4; ++mi)
#pragma unroll
      for (int ni = 0; ni < 4; ++ni)
#pragma unroll
        for (int r = 0; r < 4; ++r) {
          int row = row0 + mi * 16 + r;
          int col = col0 + ni * 16;
          int b = row >> 11, s = row & (S_ - 1);
          int kvh = col >> 6, d = col & 63;
          ((uint16_t*)C)[(size_t)((b * HKV_ + kvh) * HD_ + d) * S_ + s] = f2b(acc[mi][ni][r]);
        }
  } else {
#pragma unroll
    for (int mi = 0; mi < 4; ++mi)
#pragma unroll
      for (int ni = 0; ni < 4; ++ni) {
        int col = col0 + ni * 16;
#pragma unroll
        for (int r = 0; r < 4; ++r) {
          int row = row0 + mi * 16 + r;
          float v = acc[mi][ni][r];
          if constexpr (EPI == EPI_GELU) {
            v += ldv<F32>(bias, bias_off + col);
            float z = 0.7978845608028654f * (v + 0.044715f * v * v * v);
            z = fminf(fmaxf(z, -15.f), 15.f);
            float e = __expf(-2.f * z);
            v = 0.5f * v * (1.f + (1.f - e) / (1.f + e));   // tanh gelu (jax default)
            ((uint16_t*)C)[(size_t)row * ldc + col] = f2b(v);
          } else if constexpr (EPI == EPI_RES) {
            v += ldv<F32>(res, (size_t)row * ldc + col);
            stv<F32>(C, (size_t)row * ldc + col, v);
          } else if constexpr (EPI == EPI_ACC) {
            if (bias) v += ldv<F32>(bias, bias_off + col);
            v += ldv<F32>(C, (size_t)row * ldc + col);   // accumulate (residual lives here)
            stv<F32>(C, (size_t)row * ldc + col, v);
          }
        }
      }
  }
}

// ---------------- Flash attention: one wave per (b, head, 16-row q-tile) ----------------
// v2: (a) softmax reductions over l15 via DPP (quad_perm/row_ror) instead of
//     __shfl_xor->ds_bpermute (LDS-pipe latency chains were ~70% of iteration time);
//     (b) 64 keys per iteration (one softmax/rescale/LDS phase per 64 keys, 16 MFMA);
//     (c) XOR-swizzled P tile (row stride 128 B was same-bank on ds_read_b128);
//     (d) qt remap pairs tile k with 127-k per block -> equal block durations (causal).
__global__ __launch_bounds__(256) void attn_kernel(const uint16_t* __restrict__ q,
                                                   const uint16_t* __restrict__ k,
                                                   const uint16_t* __restrict__ vt,
                                                   uint16_t* __restrict__ o) {
  __shared__ __align__(16) uint16_t Plds[4][16 * 64];
  const int wave = threadIdx.x >> 6, lane = threadIdx.x & 63;
  const int quad = lane >> 4, l15 = lane & 15;
  const int wid = blockIdx.x * 4 + wave;
  const int j = wid & 127;
  const int qt = (j & 1) ? (127 - (j >> 1)) : (j >> 1);   // load balance: {k,127-k} pairs
  const int h = (wid >> 7) & 15;
  const int b = wid >> 11;
  const int g = h & 3;             // kv head = q head % HKV
  const int q0 = qt * 16;

  const uint16_t* qbase = q + (size_t)(b * S_ + q0 + l15) * D_ + h * HD_ + quad * 8;
  frag8 qa0 = *(const frag8*)qbase;          // Q[m=l15][d=quad*8..+7]
  frag8 qa1 = *(const frag8*)(qbase + 32);   // d+32

  f32x4 oacc[4];
  f32x4 zero = {0.f, 0.f, 0.f, 0.f};
#pragma unroll
  for (int i = 0; i < 4; i++) oacc[i] = zero;
  float m_i[4] = {-1e30f, -1e30f, -1e30f, -1e30f};
  float l_i[4] = {0.f, 0.f, 0.f, 0.f};

  uint16_t* pw = Plds[wave];
  const uint16_t* kbase = k + (size_t)(b * S_) * (HKV_ * HD_) + g * HD_;
  const uint16_t* vbase = vt + (size_t)((b * HKV_ + g) * HD_) * S_;

  const int ntiles = (q0 + 16 + 63) >> 6;   // ceil((q0+16)/64) 64-key tiles
  for (int t = 0; t < ntiles; ++t) {
    const int kt = t << 6;
    f32x4 sc[4];
#pragma unroll
    for (int f = 0; f < 4; ++f) {
      const uint16_t* kr = kbase + (size_t)(kt + 16 * f + l15) * (HKV_ * HD_) + quad * 8;
      frag8 kb0 = *(const frag8*)kr;
      frag8 kb1 = *(const frag8*)(kr + 32);
      f32x4 c = zero;
      c = __builtin_amdgcn_mfma_f32_16x16x32_bf16(qa0, kb0, c, 0, 0, 0);
      c = __builtin_amdgcn_mfma_f32_16x16x32_bf16(qa1, kb1, c, 0, 0, 0);
      sc[f] = c;
    }
    const bool needmask = (kt + 63 > q0);
    float p[4][4];   // [fragment f][row r]; score row = q0+quad*4+r, key = kt+16f+l15
#pragma unroll
    for (int f = 0; f < 4; ++f)
#pragma unroll
      for (int r = 0; r < 4; ++r) p[f][r] = sc[f][r] * 0.125f;
    if (needmask) {
#pragma unroll
      for (int r = 0; r < 4; ++r) {
        int qq = q0 + quad * 4 + r;
#pragma unroll
        for (int f = 0; f < 4; ++f)
          if (kt + 16 * f + l15 > qq) p[f][r] = -1e30f;
      }
    }
    float alpha[4];
#pragma unroll
    for (int r = 0; r < 4; ++r) {
      float rm = fmaxf(fmaxf(p[0][r], p[1][r]), fmaxf(p[2][r], p[3][r]));
      rm = row16_max(rm);                        // DPP, VALU-speed
      float mn = fmaxf(m_i[r], rm);
      alpha[r] = __expf(m_i[r] - mn);
      m_i[r] = mn;
      float rs = 0.f;
#pragma unroll
      for (int f = 0; f < 4; ++f) { p[f][r] = __expf(p[f][r] - mn); rs += p[f][r]; }
      rs = row16_sum(rs);                        // DPP
      l_i[r] = l_i[r] * alpha[r] + rs;
    }
    // C-layout P -> A-layout via per-wave swizzled LDS round trip (row=q, col=key)
#pragma unroll
    for (int r = 0; r < 4; ++r) {
      int row = quad * 4 + r;
#pragma unroll
      for (int f = 0; f < 4; ++f)
        *(uint16_t*)((char*)pw + psw(row, f * 16 + l15)) = f2b(p[f][r]);
    }
    asm volatile("s_waitcnt lgkmcnt(0)" ::: "memory");
    frag8 pa0 = *(const frag8*)((const char*)pw + psw(l15, quad * 8));        // keys kt..+31
    frag8 pa1 = *(const frag8*)((const char*)pw + psw(l15, 32 + quad * 8));   // keys kt+32..+63
#pragma unroll
    for (int d4 = 0; d4 < 4; ++d4) {
      f32x4 t4 = oacc[d4];
#pragma unroll
      for (int r = 0; r < 4; ++r) t4[r] *= alpha[r];
      const uint16_t* vr = vbase + (size_t)(d4 * 16 + l15) * S_ + kt + quad * 8;
      frag8 vb0 = *(const frag8*)vr;
      frag8 vb1 = *(const frag8*)(vr + 32);
      t4 = __builtin_amdgcn_mfma_f32_16x16x32_bf16(pa0, vb0, t4, 0, 0, 0);
      t4 = __builtin_amdgcn_mfma_f32_16x16x32_bf16(pa1, vb1, t4, 0, 0, 0);
      oacc[d4] = t4;
    }
  }
#pragma unroll
  for (int d4 = 0; d4 < 4; ++d4)
#pragma unroll
    for (int r = 0; r < 4; ++r) {
      int row = b * S_ + q0 + quad * 4 + r;
      int col = h * HD_ + d4 * 16 + l15;
      o[(size_t)row * D_ + col] = f2b(oacc[d4][r] / l_i[r]);
    }
}

// ---------------- launcher ----------------
extern "C" void kernel_launch(void* const* d_in, const int* in_sizes, int n_in,
                              void* d_out, int out_size, void* d_ws, size_t ws_size,
                              hipStream_t stream) {
  const void* x    = d_in[0];
  const void* wq   = d_in[2];
  const void* wk   = d_in[3];
  const void* wv   = d_in[4];
  const void* wo   = d_in[5];
  const void* ln1g = d_in[6];
  const void* ln1b = d_in[7];
  const void* ln2g = d_in[8];
  const void* ln2b = d_in[9];
  const void* w1   = d_in[10];
  const void* b1   = d_in[11];
  const void* w2   = d_in[12];
  const void* b2   = d_in[13];

  char* w = (char*)d_ws;
  // layout (bytes), total ~37.5 MB (fits: r3's 37.5MB layout ran; r1/r2's 62-70MB overflowed -> NaN)
  int*      flag = (int*)w;                            // 4 B (padded to 4 KB)
  float*    cosT = (float*)(w + 4096);                 // 256 KB
  float*    sinT = (float*)(w + 266240);               // 256 KB
  uint16_t* wqT  = (uint16_t*)(w + 528384);            // 2 MB
  uint16_t* wkT  = (uint16_t*)(w + 2625536);           // 512 KB
  uint16_t* wvT  = (uint16_t*)(w + 3149824);           // 512 KB
  uint16_t* woT  = (uint16_t*)(w + 3674112);           // 2 MB
  uint16_t* hbuf = (uint16_t*)(w + 5771264);           // 8 MB
  uint16_t* qbuf = (uint16_t*)(w + 14159872);          // 8 MB   } w1T after attn
  uint16_t* kbuf = (uint16_t*)(w + 22548480);          // 2 MB   } w2T after RES gemm
  uint16_t* vtb  = (uint16_t*)(w + 24645632);          // 2 MB   }
  uint16_t* obuf = (uint16_t*)(w + 26742784);          // 8 MB   }
  uint16_t* w1T  = (uint16_t*)(w + 14159872);          // 8 MB (over dead qbuf)
  uint16_t* w2T  = (uint16_t*)(w + 22548480);          // 8 MB, ends at 30937088
  uint16_t* hidq = (uint16_t*)(w + 30937088);          // 8 MB, AFTER w2T (r3 bug: started at
                                                       // 30936832, clobbering w2T's last 256 B ->
                                                       // corrupt col 1023 in MLP chunk 3, err ~9)

  detect_kernel<<<dim3(1), dim3(64), 0, stream>>>((const uint16_t*)x, flag);
  rope_table_kernel<<<dim3(256), dim3(256), 0, stream>>>(cosT, sinT);

  transpose_k<false><<<dim3(32, 32), dim3(256), 0, stream>>>(wq, wqT, 1024, 1024, flag);
  transpose_k<true ><<<dim3(32, 32), dim3(256), 0, stream>>>(wq, wqT, 1024, 1024, flag);
  transpose_k<false><<<dim3(8, 32), dim3(256), 0, stream>>>(wk, wkT, 1024, 256, flag);
  transpose_k<true ><<<dim3(8, 32), dim3(256), 0, stream>>>(wk, wkT, 1024, 256, flag);
  transpose_k<false><<<dim3(8, 32), dim3(256), 0, stream>>>(wv, wvT, 1024, 256, flag);
  transpose_k<true ><<<dim3(8, 32), dim3(256), 0, stream>>>(wv, wvT, 1024, 256, flag);
  transpose_k<false><<<dim3(32, 32), dim3(256), 0, stream>>>(wo, woT, 1024, 1024, flag);
  transpose_k<true ><<<dim3(32, 32), dim3(256), 0, stream>>>(wo, woT, 1024, 1024, flag);

  ln_kernel<false><<<dim3(4096), dim3(256), 0, stream>>>(x, ln1g, ln1b, hbuf, flag);
  ln_kernel<true ><<<dim3(4096), dim3(256), 0, stream>>>(x, ln1g, ln1b, hbuf, flag);

  gemm_bt<EPI_ROPE, false><<<dim3(32, 8), dim3(256), 0, stream>>>(hbuf, 1024, wqT, 1024, qbuf, 1024,
      4096, 1024, 1024, cosT, sinT, nullptr, 0, nullptr, nullptr);
  gemm_bt<EPI_ROPE, false><<<dim3(32, 2), dim3(256), 0, stream>>>(hbuf, 1024, wkT, 1024, kbuf, 256,
      4096, 256, 1024, cosT, sinT, nullptr, 0, nullptr, nullptr);
  gemm_bt<EPI_TRANSV, false><<<dim3(32, 2), dim3(256), 0, stream>>>(hbuf, 1024, wvT, 1024, vtb, 256,
      4096, 256, 1024, nullptr, nullptr, nullptr, 0, nullptr, nullptr);

  attn_kernel<<<dim3(1024), dim3(256), 0, stream>>>(qbuf, kbuf, vtb, obuf);

  transpose_k<false><<<dim3(128, 32), dim3(256), 0, stream>>>(w1, w1T, 1024, 4096, flag);
  transpose_k<true ><<<dim3(128, 32), dim3(256), 0, stream>>>(w1, w1T, 1024, 4096, flag);

  gemm_bt<EPI_RES, false><<<dim3(32, 8), dim3(256), 0, stream>>>(obuf, 1024, woT, 1024, d_out, 1024,
      4096, 1024, 1024, nullptr, nullptr, nullptr, 0, x, flag);
  gemm_bt<EPI_RES, true ><<<dim3(32, 8), dim3(256), 0, stream>>>(obuf, 1024, woT, 1024, d_out, 1024,
      4096, 1024, 1024, nullptr, nullptr, nullptr, 0, x, flag);

  transpose_k<false><<<dim3(32, 128), dim3(256), 0, stream>>>(w2, w2T, 4096, 1024, flag);
  transpose_k<true ><<<dim3(32, 128), dim3(256), 0, stream>>>(w2, w2T, 4096, 1024, flag);

  ln_kernel<false><<<dim3(4096), dim3(256), 0, stream>>>(d_out, ln2g, ln2b, hbuf, flag);
  ln_kernel<true ><<<dim3(4096), dim3(256), 0, stream>>>(d_out, ln2g, ln2b, hbuf, flag);

  // MLP in 4 P-chunks: hidq = gelu(hbuf @ w1T_chunk + b1_chunk); d_out += hidq @ w2T_chunk (+b2 on chunk 0)
  for (int j = 0; j < 4; ++j) {
    const uint16_t* w1c = w1T + (size_t)j * 1024 * 1024;
    const uint16_t* w2c = w2T + (size_t)j * 1024;
    const void* bb = (j == 0) ? b2 : nullptr;
    gemm_bt<EPI_GELU, false><<<dim3(32, 8), dim3(256), 0, stream>>>(hbuf, 1024, w1c, 1024, hidq, 1024,
        4096, 1024, 1024, nullptr, nullptr, b1, j * 1024, nullptr, flag);
    gemm_bt<EPI_GELU, true ><<<dim3(32, 8), dim3(256), 0, stream>>>(hbuf, 1024, w1c, 1024, hidq, 1024,
        4096, 1024, 1024, nullptr, nullptr, b1, j * 1024, nullptr, flag);
    gemm_bt<EPI_ACC, false><<<dim3(32, 8), dim3(256), 0, stream>>>(hidq, 1024, w2c, 4096, d_out, 1024,
        4096, 1024, 1024, nullptr, nullptr, bb, 0, nullptr, flag);
    gemm_bt<EPI_ACC, true ><<<dim3(32, 8), dim3(256), 0, stream>>>(hidq, 1024, w2c, 4096, d_out, 1024,
        4096, 1024, 1024, nullptr, nullptr, bb, 0, nullptr, flag);
  }
}